// Round 1
// baseline (157.597 us; speedup 1.0000x reference)
//
#include <hip/hip_runtime.h>
#include <stdint.h>
#include <stddef.h>

// ---------------------------------------------------------------------------
// StructureAwareAttention  (B=2, L=1024, D=1024, H=16, HD=64)
//   qkv = x@Wqkv + bqkv            -> q,k [B,H,L,64] bf16, v^T [B,H,64,L] bf16
//   sw  = sb@Ws + bs               -> f32 [B,L,L]
//   attn = softmax(q k^T / 8 + sw) ; ctx = attn @ v  -> bf16 [B,L,D]
//   out = ctx@Wo + bo              -> f32 [B,L,D]
// All GEMMs: bf16 MFMA 16x16x32, f32 accum. Workspace layout (bytes):
//   0: xb 4MB | 4MB: sbb 4MB | 8MB: Wqkv^T 6MB | 14MB: Ws^T 2MB | 16MB: Wo^T 2MB
//   18MB: q 4MB | 22MB: k 4MB | 26MB: v^T 4MB | 30MB: sw(f32) 8MB | 38MB: ctx 4MB
//   total 42MB (assumes ws_size >= 42MB)
// ---------------------------------------------------------------------------

typedef float f32x4 __attribute__((ext_vector_type(4)));
typedef short s16x8 __attribute__((ext_vector_type(8)));
typedef unsigned short u16x8 __attribute__((ext_vector_type(8)));

__device__ inline unsigned short f2bf(float f) {          // RNE f32 -> bf16
    unsigned u = __builtin_bit_cast(unsigned, f);
    u += 0x7fffu + ((u >> 16) & 1u);
    return (unsigned short)(u >> 16);
}

__device__ inline f32x4 mfma16(s16x8 a, s16x8 b, f32x4 c) {
    return __builtin_amdgcn_mfma_f32_16x16x32_bf16(a, b, c, 0, 0, 0);
}

__device__ inline void gld_lds16(const void* g, const void* lds_base) {
    // async global->LDS, 16B per lane, dest = wave-uniform base + lane*16
    __builtin_amdgcn_global_load_lds(
        (const __attribute__((address_space(1))) void*)(uintptr_t)g,
        (__attribute__((address_space(3))) void*)(unsigned)(uintptr_t)lds_base,
        16, 0, 0);
}

// -------------------------------- convert ----------------------------------
__global__ void cvt_bf16_k(const float* __restrict__ src, unsigned short* __restrict__ dst) {
    int i = blockIdx.x * 256 + threadIdx.x;          // each thread: 8 f32 -> 8 bf16
    const float4* s4 = (const float4*)src;
    float4 a = s4[2 * i], b = s4[2 * i + 1];
    u16x8 o;
    o[0] = f2bf(a.x); o[1] = f2bf(a.y); o[2] = f2bf(a.z); o[3] = f2bf(a.w);
    o[4] = f2bf(b.x); o[5] = f2bf(b.y); o[6] = f2bf(b.z); o[7] = f2bf(b.w);
    *(u16x8*)(dst + (size_t)i * 8) = o;
}

// ---------------------- weight transpose: W[K][N] -> Wt[N][K] bf16 ----------
__global__ __launch_bounds__(256) void transpose_w_k(const float* __restrict__ W,
                                                     unsigned short* __restrict__ Wt, int N) {
    __shared__ float tile[64][65];
    const int t = threadIdx.x;
    const int n0 = blockIdx.x * 64, k0 = blockIdx.y * 64;
    const int lr = t >> 4, lc = (t & 15) * 4;
#pragma unroll
    for (int rr = 0; rr < 4; rr++) {
        int r = lr + rr * 16;
        float4 v = *(const float4*)(W + (size_t)(k0 + r) * N + n0 + lc);
        tile[r][lc] = v.x; tile[r][lc + 1] = v.y; tile[r][lc + 2] = v.z; tile[r][lc + 3] = v.w;
    }
    __syncthreads();
    const int wn = t >> 3, wk = (t & 7) * 8;
#pragma unroll
    for (int rr = 0; rr < 2; rr++) {
        int n = wn + rr * 32;
        u16x8 o;
#pragma unroll
        for (int j = 0; j < 8; j++) o[j] = f2bf(tile[wk + j][n]);
        *(u16x8*)(Wt + (size_t)(n0 + n) * 1024 + k0 + wk) = o;
    }
}

// ------------------------------- GEMM --------------------------------------
// C[M,N] = A[M,1024] @ Bt[N,1024]^T + bias.  128x128 tile, BK=32, 4 waves.
// EPI 0: scatter bf16 into q/k [B,H,L,64] and v^T [B,H,64,L] (N=3072)
// EPI 1: f32 row-major [M][1024]
template <int EPI>
__global__ __launch_bounds__(256) void gemm_k(const unsigned short* __restrict__ A,
                                              const unsigned short* __restrict__ Bt,
                                              const float* __restrict__ bias,
                                              unsigned short* __restrict__ q,
                                              unsigned short* __restrict__ kk_,
                                              unsigned short* __restrict__ vt,
                                              float* __restrict__ outf) {
    __shared__ unsigned short lA[4096], lB[4096];   // 128 x 32 bf16 each
    const int t = threadIdx.x;
    const int wave = t >> 6, lane = t & 63, c = lane & 15, g = lane >> 4;
    const int bn0 = blockIdx.x * 128, bm0 = blockIdx.y * 128;
    const int wr = (wave >> 1) * 64, wc = (wave & 1) * 64;
    // staging map: slot s -> row=s>>2, phys chunk p=s&3 holds logical chunk p^((row>>1)&3)
    const int row = t >> 2, p = t & 3;
    const int gg = p ^ ((row >> 1) & 3);
    const size_t aoff = (size_t)(bm0 + row) * 1024 + gg * 8;
    const size_t boff = (size_t)(bn0 + row) * 1024 + gg * 8;
    char* lAb = (char*)lA; char* lBb = (char*)lB;

    f32x4 acc[4][4];
#pragma unroll
    for (int i = 0; i < 4; i++)
#pragma unroll
        for (int j = 0; j < 4; j++) acc[i][j] = {0.f, 0.f, 0.f, 0.f};

    for (int kt = 0; kt < 1024; kt += 32) {
        __syncthreads();
        gld_lds16(A + aoff + kt,                      lAb + wave * 1024);
        gld_lds16(A + aoff + (size_t)64 * 1024 + kt,  lAb + 4096 + wave * 1024);
        gld_lds16(Bt + boff + kt,                     lBb + wave * 1024);
        gld_lds16(Bt + boff + (size_t)64 * 1024 + kt, lBb + 4096 + wave * 1024);
        __syncthreads();
        s16x8 af[4], bfr[4];
#pragma unroll
        for (int i = 0; i < 4; i++) {
            int r_ = wr + i * 16 + c;
            af[i] = *(const s16x8*)(lAb + r_ * 64 + ((g ^ ((r_ >> 1) & 3)) << 4));
        }
#pragma unroll
        for (int j = 0; j < 4; j++) {
            int r_ = wc + j * 16 + c;
            bfr[j] = *(const s16x8*)(lBb + r_ * 64 + ((g ^ ((r_ >> 1) & 3)) << 4));
        }
#pragma unroll
        for (int i = 0; i < 4; i++)
#pragma unroll
            for (int j = 0; j < 4; j++)
                acc[i][j] = mfma16(af[i], bfr[j], acc[i][j]);
    }

#pragma unroll
    for (int i = 0; i < 4; i++) {
#pragma unroll
        for (int j = 0; j < 4; j++) {
            const int n = bn0 + wc + j * 16 + c;
            const float bv = bias[n];
#pragma unroll
            for (int r = 0; r < 4; r++) {
                const int m = bm0 + wr + i * 16 + g * 4 + r;
                float v = acc[i][j][r] + bv;
                if (EPI == 0) {
                    const int sel = n >> 10, h = (n >> 6) & 15, d = n & 63;
                    const int b_ = m >> 10, l_ = m & 1023;
                    const size_t bh = (size_t)((b_ << 4) + h);
                    unsigned short hv = f2bf(v);
                    if (sel == 0)      q[(bh * 1024 + l_) * 64 + d] = hv;
                    else if (sel == 1) kk_[(bh * 1024 + l_) * 64 + d] = hv;
                    else               vt[(bh * 64 + d) * 1024 + l_] = hv;
                } else {
                    outf[(size_t)m * 1024 + n] = v;
                }
            }
        }
    }
}

// ------------------------------ attention ----------------------------------
// 1 block = (b,h, 64 q-rows); wave w owns 16 q-rows. KVBLK=32, online softmax
// in exp2 domain. P goes through padded per-wave LDS tile to form A-fragments.
__global__ __launch_bounds__(256) void attn_k(const unsigned short* __restrict__ q,
                                              const unsigned short* __restrict__ k,
                                              const unsigned short* __restrict__ vt,
                                              const float* __restrict__ sw,
                                              unsigned short* __restrict__ ctx) {
    __shared__ unsigned short lP[4][640];            // per wave: 16 rows x 40 (pad)
    const int t = threadIdx.x, wave = t >> 6, lane = t & 63, c = lane & 15, g = lane >> 4;
    const int blk = blockIdx.x;
    const int qt = blk & 15, bh = blk >> 4, b_ = bh >> 4, h = bh & 15;
    const int qr = qt * 64 + wave * 16;

    const unsigned short* qbase = q + ((size_t)bh * 1024 + qr) * 64;
    s16x8 aq0 = *(const s16x8*)(qbase + (size_t)c * 64 + g * 8);
    s16x8 aq1 = *(const s16x8*)(qbase + (size_t)c * 64 + 32 + g * 8);

    const unsigned short* kb0 = k + (size_t)bh * 1024 * 64;
    const unsigned short* vb0 = vt + (size_t)bh * 64 * 1024;
    const float* swb = sw + ((size_t)b_ * 1024 + qr + g * 4) * 1024;
    unsigned short* wp = lP[wave];

    const float SCQ = 0.125f * 1.4426950408889634f;  // (1/sqrt(64)) * log2(e)
    const float L2E = 1.4426950408889634f;

    float mr[4], lr[4];
    f32x4 acc[4];
#pragma unroll
    for (int r = 0; r < 4; r++) { mr[r] = -1e30f; lr[r] = 0.0f; }
#pragma unroll
    for (int nf = 0; nf < 4; nf++) acc[nf] = {0.f, 0.f, 0.f, 0.f};

    for (int kv0 = 0; kv0 < 1024; kv0 += 32) {
        f32x4 s0 = {0.f, 0.f, 0.f, 0.f}, s1 = {0.f, 0.f, 0.f, 0.f};
        {
            const unsigned short* kb = kb0 + (size_t)kv0 * 64;
            s16x8 b00 = *(const s16x8*)(kb + c * 64 + g * 8);
            s16x8 b01 = *(const s16x8*)(kb + c * 64 + 32 + g * 8);
            s16x8 b10 = *(const s16x8*)(kb + (16 + c) * 64 + g * 8);
            s16x8 b11 = *(const s16x8*)(kb + (16 + c) * 64 + 32 + g * 8);
            s0 = mfma16(aq0, b00, s0); s0 = mfma16(aq1, b01, s0);
            s1 = mfma16(aq0, b10, s1); s1 = mfma16(aq1, b11, s1);
        }
        float p0[4], p1[4];
#pragma unroll
        for (int r = 0; r < 4; r++) {
            float z0 = s0[r] * SCQ + swb[(size_t)r * 1024 + kv0 + c] * L2E;
            float z1 = s1[r] * SCQ + swb[(size_t)r * 1024 + kv0 + 16 + c] * L2E;
            float tm = fmaxf(z0, z1);
            tm = fmaxf(tm, __shfl_xor(tm, 1, 64));
            tm = fmaxf(tm, __shfl_xor(tm, 2, 64));
            tm = fmaxf(tm, __shfl_xor(tm, 4, 64));
            tm = fmaxf(tm, __shfl_xor(tm, 8, 64));
            float mn = fmaxf(mr[r], tm);
            float f = __builtin_amdgcn_exp2f(mr[r] - mn);
            mr[r] = mn;
            p0[r] = __builtin_amdgcn_exp2f(z0 - mn);
            p1[r] = __builtin_amdgcn_exp2f(z1 - mn);
            float rs = p0[r] + p1[r];
            rs += __shfl_xor(rs, 1, 64);
            rs += __shfl_xor(rs, 2, 64);
            rs += __shfl_xor(rs, 4, 64);
            rs += __shfl_xor(rs, 8, 64);
            lr[r] = lr[r] * f + rs;
#pragma unroll
            for (int nf = 0; nf < 4; nf++) acc[nf][r] *= f;
        }
        // P -> LDS (row = g*4+r, cols c and c+16), then A-fragment read (same wave)
#pragma unroll
        for (int r = 0; r < 4; r++) {
            wp[(g * 4 + r) * 40 + c] = f2bf(p0[r]);
            wp[(g * 4 + r) * 40 + 16 + c] = f2bf(p1[r]);
        }
        s16x8 ap = *(const s16x8*)((const char*)wp + c * 80 + g * 16);
#pragma unroll
        for (int nf = 0; nf < 4; nf++) {
            s16x8 bv = *(const s16x8*)(vb0 + (size_t)(nf * 16 + c) * 1024 + kv0 + g * 8);
            acc[nf] = mfma16(ap, bv, acc[nf]);
        }
    }
#pragma unroll
    for (int r = 0; r < 4; r++) {
        float inv = 1.0f / lr[r];
        const size_t orow = ((size_t)b_ * 1024 + qr + g * 4 + r) * 1024 + h * 64;
#pragma unroll
        for (int nf = 0; nf < 4; nf++)
            ctx[orow + nf * 16 + c] = f2bf(acc[nf][r] * inv);
    }
}

// ------------------------------- launch ------------------------------------
extern "C" void kernel_launch(void* const* d_in, const int* in_sizes, int n_in,
                              void* d_out, int out_size, void* d_ws, size_t ws_size,
                              hipStream_t stream) {
    const float* x    = (const float*)d_in[0];
    const float* sb   = (const float*)d_in[1];
    const float* Wqkv = (const float*)d_in[2];
    const float* bqkv = (const float*)d_in[3];
    const float* Ws   = (const float*)d_in[4];
    const float* bs   = (const float*)d_in[5];
    const float* Wo   = (const float*)d_in[6];
    const float* bo   = (const float*)d_in[7];
    float* out = (float*)d_out;

    char* ws = (char*)d_ws;
    unsigned short* xb    = (unsigned short*)(ws);
    unsigned short* sbb   = (unsigned short*)(ws + ((size_t)4 << 20));
    unsigned short* wqkvt = (unsigned short*)(ws + ((size_t)8 << 20));
    unsigned short* wst   = (unsigned short*)(ws + ((size_t)14 << 20));
    unsigned short* wot   = (unsigned short*)(ws + ((size_t)16 << 20));
    unsigned short* qb    = (unsigned short*)(ws + ((size_t)18 << 20));
    unsigned short* kb    = (unsigned short*)(ws + ((size_t)22 << 20));
    unsigned short* vtb   = (unsigned short*)(ws + ((size_t)26 << 20));
    float*          swf   = (float*)        (ws + ((size_t)30 << 20));
    unsigned short* ctxb  = (unsigned short*)(ws + ((size_t)38 << 20));

    cvt_bf16_k<<<dim3(1024), dim3(256), 0, stream>>>(x, xb);
    cvt_bf16_k<<<dim3(1024), dim3(256), 0, stream>>>(sb, sbb);
    transpose_w_k<<<dim3(48, 16), dim3(256), 0, stream>>>(Wqkv, wqkvt, 3072);
    transpose_w_k<<<dim3(16, 16), dim3(256), 0, stream>>>(Ws, wst, 1024);
    transpose_w_k<<<dim3(16, 16), dim3(256), 0, stream>>>(Wo, wot, 1024);
    gemm_k<0><<<dim3(24, 16), dim3(256), 0, stream>>>(xb, wqkvt, bqkv, qb, kb, vtb, (float*)nullptr);
    gemm_k<1><<<dim3(8, 16), dim3(256), 0, stream>>>(sbb, wst, bs,
                                                     (unsigned short*)nullptr, (unsigned short*)nullptr,
                                                     (unsigned short*)nullptr, swf);
    attn_k<<<dim3(512), dim3(256), 0, stream>>>(qb, kb, vtb, swf, ctxb);
    gemm_k<1><<<dim3(8, 16), dim3(256), 0, stream>>>(ctxb, wot, bo,
                                                     (unsigned short*)nullptr, (unsigned short*)nullptr,
                                                     (unsigned short*)nullptr, out);
}